// Round 2
// baseline (14102.625 us; speedup 1.0000x reference)
//
#include <hip/hip_runtime.h>
#include <hip/hip_bf16.h>
#include <math.h>

#define CMDN   2
#define LIDARN 360
#define HN     256
#define TN     50
#define BATCH  2048
#define NG     (4*HN)        // 1024 gate columns
#define KXN    (LIDARN+CMDN) // 362 (Wih K-dim, both enc and dec)
#define KTOT   (KXN+HN)      // 618 total K

// ---------------------------------------------------------------------------
// Gates GEMM: gates[b][j] = bias[j] + sum_k A[b][k] * W[j][k]
// A = virtual concat [ x0 (K0, stride lda0) | x1 (K1, stride lda1) | h (HN) ]
// W = virtual concat [ Wih (K=KXN) | Whh (K=HN) ]   (K0+K1 == KXN always)
// Tile: BM=64 x BN=64, BK=32, 256 threads, 4x4 microtile.
// ---------------------------------------------------------------------------
__global__ __launch_bounds__(256) void gates_gemm(
    const float* __restrict__ x0, int lda0, int K0,
    const float* __restrict__ x1, int lda1, int K1,
    const float* __restrict__ h,
    const float* __restrict__ Wih,
    const float* __restrict__ Whh,
    const float* __restrict__ bias,
    float* __restrict__ gates)
{
    __shared__ float As[64][33];
    __shared__ float Bs[64][33];

    const int tx = threadIdx.x;           // 0..15
    const int ty = threadIdx.y;           // 0..15
    const int tid = ty * 16 + tx;
    const int r0 = blockIdx.y * 64;       // batch-row tile
    const int j0 = blockIdx.x * 64;       // gate-col tile

    float acc[4][4] = {};

    const int K01 = K0 + K1;              // == KXN

    for (int k0 = 0; k0 < KTOT; k0 += 32) {
        // Cooperative load of A-tile and W-tile (coalesced in k).
        #pragma unroll
        for (int i = 0; i < 8; ++i) {
            int idx = i * 256 + tid;
            int r   = idx >> 5;           // 0..63
            int kk  = idx & 31;
            int k   = k0 + kk;

            // A side
            float v = 0.f;
            int rg = r0 + r;
            if (k < K0)          v = x0[(size_t)rg * lda0 + k];
            else if (k < K01)    v = x1[(size_t)rg * lda1 + (k - K0)];
            else if (k < KTOT)   v = h[(size_t)rg * HN + (k - K01)];
            As[r][kk] = v;

            // W side
            float w = 0.f;
            int jg = j0 + r;
            if (k < KXN)         w = Wih[(size_t)jg * KXN + k];
            else if (k < KTOT)   w = Whh[(size_t)jg * HN + (k - KXN)];
            Bs[r][kk] = w;
        }
        __syncthreads();

        #pragma unroll
        for (int kk = 0; kk < 32; ++kk) {
            float a[4], bb[4];
            #pragma unroll
            for (int i = 0; i < 4; ++i) a[i]  = As[ty * 4 + i][kk];
            #pragma unroll
            for (int j = 0; j < 4; ++j) bb[j] = Bs[tx * 4 + j][kk];
            #pragma unroll
            for (int i = 0; i < 4; ++i)
                #pragma unroll
                for (int j = 0; j < 4; ++j)
                    acc[i][j] += a[i] * bb[j];
        }
        __syncthreads();
    }

    #pragma unroll
    for (int i = 0; i < 4; ++i) {
        int rg = r0 + ty * 4 + i;
        #pragma unroll
        for (int j = 0; j < 4; ++j) {
            int jg = j0 + tx * 4 + j;
            gates[(size_t)rg * NG + jg] = acc[i][j] + bias[jg];
        }
    }
}

// ---------------------------------------------------------------------------
// LSTM cell pointwise: c = sig(f)*c + sig(i)*tanh(g); h = sig(o)*tanh(c)
// ---------------------------------------------------------------------------
__global__ __launch_bounds__(256) void cell_kernel(
    const float* __restrict__ gates,
    float* __restrict__ h,
    float* __restrict__ c)
{
    int idx = blockIdx.x * 256 + threadIdx.x;   // < BATCH*HN
    int b = idx >> 8;
    int j = idx & 255;
    const float* g = gates + (size_t)b * NG;
    float gi = g[j];
    float gf = g[256 + j];
    float gg = g[512 + j];
    float go = g[768 + j];
    float cc = c[idx];
    float si = 1.f / (1.f + expf(-gi));
    float sf = 1.f / (1.f + expf(-gf));
    float so = 1.f / (1.f + expf(-go));
    cc = sf * cc + si * tanhf(gg);
    float hh = so * tanhf(cc);
    c[idx] = cc;
    h[idx] = hh;
}

// ---------------------------------------------------------------------------
// Output projection: lidar[b][n] = bias[n] + sum_k h[b][k] * W[n][k]
// Writes fp32 feedback buffer + fp32 d_out slice for step t.
// ---------------------------------------------------------------------------
__global__ __launch_bounds__(256) void outproj_gemm(
    const float* __restrict__ h,
    const float* __restrict__ W,      // [360][256]
    const float* __restrict__ bias,   // [360]
    float* __restrict__ lidar,        // [B][360]
    float* __restrict__ out,          // [B][T][360]
    int t)
{
    __shared__ float As[64][33];
    __shared__ float Bs[64][33];

    const int tx = threadIdx.x;
    const int ty = threadIdx.y;
    const int tid = ty * 16 + tx;
    const int r0 = blockIdx.y * 64;
    const int j0 = blockIdx.x * 64;   // lidar-col tile (6 tiles, last partial)

    float acc[4][4] = {};

    for (int k0 = 0; k0 < HN; k0 += 32) {
        #pragma unroll
        for (int i = 0; i < 8; ++i) {
            int idx = i * 256 + tid;
            int r   = idx >> 5;
            int kk  = idx & 31;
            int k   = k0 + kk;
            As[r][kk] = h[(size_t)(r0 + r) * HN + k];
            int jg = j0 + r;
            Bs[r][kk] = (jg < LIDARN) ? W[(size_t)jg * HN + k] : 0.f;
        }
        __syncthreads();

        #pragma unroll
        for (int kk = 0; kk < 32; ++kk) {
            float a[4], bb[4];
            #pragma unroll
            for (int i = 0; i < 4; ++i) a[i]  = As[ty * 4 + i][kk];
            #pragma unroll
            for (int j = 0; j < 4; ++j) bb[j] = Bs[tx * 4 + j][kk];
            #pragma unroll
            for (int i = 0; i < 4; ++i)
                #pragma unroll
                for (int j = 0; j < 4; ++j)
                    acc[i][j] += a[i] * bb[j];
        }
        __syncthreads();
    }

    #pragma unroll
    for (int i = 0; i < 4; ++i) {
        int rg = r0 + ty * 4 + i;
        #pragma unroll
        for (int j = 0; j < 4; ++j) {
            int jg = j0 + tx * 4 + j;
            if (jg < LIDARN) {
                float v = acc[i][j] + bias[jg];
                lidar[(size_t)rg * LIDARN + jg] = v;
                out[(size_t)rg * (TN * LIDARN) + (size_t)t * LIDARN + jg] = v;
            }
        }
    }
}

// ---------------------------------------------------------------------------
// Init: h = c = 0; lidar = past_data[:, T-1, CMD:]
// ---------------------------------------------------------------------------
__global__ __launch_bounds__(256) void init_kernel(
    const float* __restrict__ past,
    float* __restrict__ h,
    float* __restrict__ c,
    float* __restrict__ lidar)
{
    int idx = blockIdx.x * 256 + threadIdx.x;
    if (idx < BATCH * HN) {
        h[idx] = 0.f;
        c[idx] = 0.f;
    }
    if (idx < BATCH * LIDARN) {
        int b = idx / LIDARN;
        int n = idx - b * LIDARN;
        lidar[idx] = past[(size_t)b * TN * KXN + (size_t)(TN - 1) * KXN + CMDN + n];
    }
}

extern "C" void kernel_launch(void* const* d_in, const int* in_sizes, int n_in,
                              void* d_out, int out_size, void* d_ws, size_t ws_size,
                              hipStream_t stream)
{
    const float* past = (const float*)d_in[0];
    const float* cmds = (const float*)d_in[1];
    const float* eWih = (const float*)d_in[2];
    const float* eWhh = (const float*)d_in[3];
    const float* eb   = (const float*)d_in[4];
    const float* dWih = (const float*)d_in[5];
    const float* dWhh = (const float*)d_in[6];
    const float* db   = (const float*)d_in[7];
    const float* oW   = (const float*)d_in[8];
    const float* ob   = (const float*)d_in[9];
    float* out = (float*)d_out;

    float* ws    = (float*)d_ws;
    float* h     = ws;                          // B*H
    float* c     = h + (size_t)BATCH * HN;      // B*H
    float* gates = c + (size_t)BATCH * HN;      // B*4H
    float* lidar = gates + (size_t)BATCH * NG;  // B*360

    init_kernel<<<(BATCH * LIDARN + 255) / 256, 256, 0, stream>>>(past, h, c, lidar);

    const dim3 gblk(16, 16);
    const dim3 ggrid(NG / 64, BATCH / 64);      // 16 x 32 = 512 blocks
    const dim3 ogrid((LIDARN + 63) / 64, BATCH / 64); // 6 x 32

    for (int t = 0; t < TN; ++t) {
        gates_gemm<<<ggrid, gblk, 0, stream>>>(
            past + (size_t)t * KXN, TN * KXN, KXN,
            nullptr, 0, 0,
            h, eWih, eWhh, eb, gates);
        cell_kernel<<<BATCH * HN / 256, 256, 0, stream>>>(gates, h, c);
    }

    for (int t = 0; t < TN; ++t) {
        gates_gemm<<<ggrid, gblk, 0, stream>>>(
            lidar, LIDARN, LIDARN,
            cmds + (size_t)t * CMDN, TN * CMDN, CMDN,
            h, dWih, dWhh, db, gates);
        cell_kernel<<<BATCH * HN / 256, 256, 0, stream>>>(gates, h, c);
        outproj_gemm<<<ogrid, gblk, 0, stream>>>(h, oW, ob, lidar, out, t);
    }
}

// Round 3
// 2830.211 us; speedup vs baseline: 4.9829x; 4.9829x over previous
//
#include <hip/hip_runtime.h>
#include <hip/hip_bf16.h>
#include <math.h>

#define CMDN   2
#define LIDARN 360
#define HN     256
#define TN     50
#define BATCH  2048
#define KXN    362            // CMD+LIDAR
#define XROW   (TN*KXN)       // 18100, past_data row stride (floats)
#define KPAD   640            // padded K: [x 0..362 | pad ..384 | h ..640]
#define HOFF   384
#define LCW    384            // lidarcat width: [lidar 360 | cmd 2 | pad 22]
#define BM     64
#define BN     64
#define LDSP   40             // LDS k-stride (bf16 elems) => 80B rows, even bank spread

typedef __attribute__((ext_vector_type(8))) short bf16x8;
typedef __attribute__((ext_vector_type(4))) float f32x4;

// fp32 -> bf16 round-to-nearest-even
__device__ inline unsigned short f2b(float f) {
    unsigned int x = __builtin_bit_cast(unsigned int, f);
    x += 0x7FFFu + ((x >> 16) & 1u);
    return (unsigned short)(x >> 16);
}

// ---------------------------------------------------------------------------
// Fused gates GEMM + LSTM cell.
// gates[b][j] = bias[j] + sum_k A[b][k] * Wcat[j][k],  j interleaved per block:
// block col c (0..63) -> gate g=c&3, unit u=u0+(c>>2).  Cell via 4-lane shfl.
// A: ENC: [past_t fp32 (362) | 0 | h bf16]; DEC: [lidarcat bf16 (384) | h bf16]
// ---------------------------------------------------------------------------
template<bool ENC>
__global__ __launch_bounds__(256) void gates_mfma(
    const float* __restrict__ xf,            // ENC: past + t*KXN
    const unsigned short* __restrict__ xb,   // DEC: lidarcat
    const unsigned short* __restrict__ hin,  // [B][H] bf16
    const unsigned short* __restrict__ W,    // [1024][KPAD] bf16
    const float* __restrict__ bias,          // [1024]
    float* __restrict__ cst,                 // [B][H] f32 (rw)
    unsigned short* __restrict__ hout)       // [B][H] bf16
{
    __shared__ __align__(16) unsigned short Al[BM][LDSP];
    __shared__ __align__(16) unsigned short Bl[BN][LDSP];

    const int tid  = threadIdx.x;
    const int lane = tid & 63;
    const int wv   = tid >> 6;              // 0..3
    const int wm   = wv >> 1, wn = wv & 1;  // wave grid 2x2
    const int r0   = blockIdx.y * BM;       // batch rows
    const int u0   = blockIdx.x * 16;       // units

    const int srow = tid >> 2;              // 0..63 staging row
    const int sq   = tid & 3;               // k-quarter
    const int bj   = ((srow & 3) << 8) + u0 + (srow >> 2);  // Wcat row for tile col srow
    const unsigned short* wrow = W + (size_t)bj * KPAD + sq * 8;

    const int l15 = lane & 15;
    const int kb  = (lane >> 4) << 3;       // fragment k-block: 0,8,16,24

    f32x4 acc[2][2] = {};

    auto stageB = [&](int k0) {
        *(bf16x8*)&Bl[srow][sq * 8] = *(const bf16x8*)(wrow + k0);
    };
    auto compute = [&]() {
        __syncthreads();
        bf16x8 a0 = *(const bf16x8*)&Al[wm * 32 +      l15][kb];
        bf16x8 a1 = *(const bf16x8*)&Al[wm * 32 + 16 + l15][kb];
        bf16x8 b0 = *(const bf16x8*)&Bl[wn * 32 +      l15][kb];
        bf16x8 b1 = *(const bf16x8*)&Bl[wn * 32 + 16 + l15][kb];
        acc[0][0] = __builtin_amdgcn_mfma_f32_16x16x32_bf16(a0, b0, acc[0][0], 0, 0, 0);
        acc[0][1] = __builtin_amdgcn_mfma_f32_16x16x32_bf16(a0, b1, acc[0][1], 0, 0, 0);
        acc[1][0] = __builtin_amdgcn_mfma_f32_16x16x32_bf16(a1, b0, acc[1][0], 0, 0, 0);
        acc[1][1] = __builtin_amdgcn_mfma_f32_16x16x32_bf16(a1, b1, acc[1][1], 0, 0, 0);
        __syncthreads();
    };

    if (ENC) {
        // phase 1: k0 = 0..320, pure fp32 source (k+31 <= 351 < 362)
        for (int k0 = 0; k0 < 352; k0 += 32) {
            stageB(k0);
            const float* p = xf + (size_t)(r0 + srow) * XROW + k0 + sq * 8;
            float2 v0 = *(const float2*)(p);
            float2 v1 = *(const float2*)(p + 2);
            float2 v2 = *(const float2*)(p + 4);
            float2 v3 = *(const float2*)(p + 6);
            bf16x8 t;
            t[0] = (short)f2b(v0.x); t[1] = (short)f2b(v0.y);
            t[2] = (short)f2b(v1.x); t[3] = (short)f2b(v1.y);
            t[4] = (short)f2b(v2.x); t[5] = (short)f2b(v2.y);
            t[6] = (short)f2b(v3.x); t[7] = (short)f2b(v3.y);
            *(bf16x8*)&Al[srow][sq * 8] = t;
            compute();
        }
        // phase 2: k0 = 352 partial (k 352..361 valid, 362..383 -> 0; W pad is 0 anyway)
        {
            stageB(352);
            const float* p = xf + (size_t)(r0 + srow) * XROW;
            bf16x8 t;
            #pragma unroll
            for (int e = 0; e < 8; ++e) {
                int k = 352 + sq * 8 + e;
                t[e] = (k < KXN) ? (short)f2b(p[k]) : (short)0;
            }
            *(bf16x8*)&Al[srow][sq * 8] = t;
            compute();
        }
    } else {
        // decoder: lidarcat bf16, 12 full steps (k0 0..352)
        for (int k0 = 0; k0 < HOFF; k0 += 32) {
            stageB(k0);
            *(bf16x8*)&Al[srow][sq * 8] =
                *(const bf16x8*)&xb[(size_t)(r0 + srow) * LCW + k0 + sq * 8];
            compute();
        }
    }
    // phase 3: h segment, bf16
    for (int k0 = HOFF; k0 < KPAD; k0 += 32) {
        stageB(k0);
        *(bf16x8*)&Al[srow][sq * 8] =
            *(const bf16x8*)&hin[(size_t)(r0 + srow) * HN + (k0 - HOFF) + sq * 8];
        compute();
    }

    // ---- fused cell epilogue ----
    #pragma unroll
    for (int mi = 0; mi < 2; ++mi) {
        const int rowb = r0 + wm * 32 + mi * 16 + ((lane >> 4) << 2);
        #pragma unroll
        for (int ni = 0; ni < 2; ++ni) {
            const int cl = wn * 32 + ni * 16 + l15;
            const int g  = cl & 3;                 // 0=i 1=f 2=g 3=o
            const int u  = u0 + (cl >> 2);
            const float bs = bias[(g << 8) + u];
            #pragma unroll
            for (int r = 0; r < 4; ++r) {
                float v   = acc[mi][ni][r] + bs;
                float act = (g == 2) ? tanhf(v) : 1.f / (1.f + expf(-v));
                float a1  = __shfl_xor(act, 1);
                float a2  = __shfl_xor(act, 2);
                float a3  = __shfl_xor(act, 3);
                if (g == 0) {                      // lane holds i; a1=f, a2=g, a3=o
                    size_t idx = (size_t)(rowb + r) * HN + u;
                    float cc = a1 * cst[idx] + act * a2;
                    float hh = a3 * tanhf(cc);
                    cst[idx]  = cc;
                    hout[idx] = f2b(hh);
                }
            }
        }
    }
}

// ---------------------------------------------------------------------------
// Output projection MFMA: lidar[b][n] = ob[n] + sum_k h[b][k]*oWp[n][k]
// Writes fp32 d_out + bf16 lidarcat feedback + injects cmd[t+1] into cols 360/361.
// ---------------------------------------------------------------------------
__global__ __launch_bounds__(256) void outproj_mfma(
    const unsigned short* __restrict__ hin,   // [B][H] bf16
    const unsigned short* __restrict__ oWp,   // [384][256] bf16 (rows >=360 zero)
    const float* __restrict__ ob,             // [360]
    const float* __restrict__ cmds,           // [B][T][2] fp32
    float* __restrict__ out,                  // [B][T][360]
    unsigned short* __restrict__ lidarcat,    // [B][384] bf16
    int t)
{
    __shared__ __align__(16) unsigned short Al[BM][LDSP];
    __shared__ __align__(16) unsigned short Bl[BN][LDSP];

    const int tid  = threadIdx.x;
    const int lane = tid & 63;
    const int wv   = tid >> 6;
    const int wm   = wv >> 1, wn = wv & 1;
    const int r0   = blockIdx.y * BM;
    const int n0   = blockIdx.x * BN;

    const int srow = tid >> 2;
    const int sq   = tid & 3;
    const unsigned short* wrow = oWp + (size_t)(n0 + srow) * HN + sq * 8;

    const int l15 = lane & 15;
    const int kb  = (lane >> 4) << 3;

    f32x4 acc[2][2] = {};

    for (int k0 = 0; k0 < HN; k0 += 32) {
        *(bf16x8*)&Bl[srow][sq * 8] = *(const bf16x8*)(wrow + k0);
        *(bf16x8*)&Al[srow][sq * 8] =
            *(const bf16x8*)&hin[(size_t)(r0 + srow) * HN + k0 + sq * 8];
        __syncthreads();
        bf16x8 a0 = *(const bf16x8*)&Al[wm * 32 +      l15][kb];
        bf16x8 a1 = *(const bf16x8*)&Al[wm * 32 + 16 + l15][kb];
        bf16x8 b0 = *(const bf16x8*)&Bl[wn * 32 +      l15][kb];
        bf16x8 b1 = *(const bf16x8*)&Bl[wn * 32 + 16 + l15][kb];
        acc[0][0] = __builtin_amdgcn_mfma_f32_16x16x32_bf16(a0, b0, acc[0][0], 0, 0, 0);
        acc[0][1] = __builtin_amdgcn_mfma_f32_16x16x32_bf16(a0, b1, acc[0][1], 0, 0, 0);
        acc[1][0] = __builtin_amdgcn_mfma_f32_16x16x32_bf16(a1, b0, acc[1][0], 0, 0, 0);
        acc[1][1] = __builtin_amdgcn_mfma_f32_16x16x32_bf16(a1, b1, acc[1][1], 0, 0, 0);
        __syncthreads();
    }

    #pragma unroll
    for (int mi = 0; mi < 2; ++mi) {
        const int rowb = r0 + wm * 32 + mi * 16 + ((lane >> 4) << 2);
        #pragma unroll
        for (int ni = 0; ni < 2; ++ni) {
            const int n = n0 + wn * 32 + ni * 16 + l15;
            #pragma unroll
            for (int r = 0; r < 4; ++r) {
                const int b = rowb + r;
                if (n < LIDARN) {
                    float v = acc[mi][ni][r] + ob[n];
                    out[(size_t)b * (TN * LIDARN) + (size_t)t * LIDARN + n] = v;
                    lidarcat[(size_t)b * LCW + n] = f2b(v);
                } else if (n < 362 && t + 1 < TN) {
                    float cv = cmds[(size_t)b * (TN * CMDN) + (t + 1) * CMDN + (n - LIDARN)];
                    lidarcat[(size_t)b * LCW + n] = f2b(cv);
                }
            }
        }
    }
}

// ---------------------------------------------------------------------------
// One-time prep: pack weights to bf16 [1024][KPAD] (+ padded outproj weights)
// ---------------------------------------------------------------------------
__global__ __launch_bounds__(256) void convert_w(
    const float* __restrict__ eWih, const float* __restrict__ eWhh,
    const float* __restrict__ dWih, const float* __restrict__ dWhh,
    const float* __restrict__ oW,
    unsigned short* __restrict__ Wenc, unsigned short* __restrict__ Wdec,
    unsigned short* __restrict__ oWp)
{
    int idx = blockIdx.x * 256 + threadIdx.x;
    if (idx < 1024 * KPAD) {
        int j = idx / KPAD, k = idx - j * KPAD;
        float ve, vd;
        if (k < KXN)       { ve = eWih[(size_t)j * KXN + k]; vd = dWih[(size_t)j * KXN + k]; }
        else if (k < HOFF) { ve = 0.f;                        vd = 0.f; }
        else               { ve = eWhh[(size_t)j * HN + k - HOFF];
                             vd = dWhh[(size_t)j * HN + k - HOFF]; }
        Wenc[idx] = f2b(ve);
        Wdec[idx] = f2b(vd);
    }
    if (idx < 384 * HN) {
        int j = idx / HN, k = idx - j * HN;
        oWp[idx] = f2b(j < LIDARN ? oW[(size_t)j * HN + k] : 0.f);
    }
}

// ---------------------------------------------------------------------------
// Init: h0 = 0, c = 0, lidarcat = [bf16(past[:, -1, 2:]) | bf16(cmd[:,0,:]) | 0]
// ---------------------------------------------------------------------------
__global__ __launch_bounds__(256) void init_state(
    const float* __restrict__ past, const float* __restrict__ cmds,
    unsigned short* __restrict__ h0, float* __restrict__ cst,
    unsigned short* __restrict__ lidarcat)
{
    int idx = blockIdx.x * 256 + threadIdx.x;   // over BATCH*LCW
    if (idx < BATCH * LCW) {
        int b = idx / LCW, n = idx - b * LCW;
        float v;
        if (n < LIDARN)   v = past[(size_t)b * XROW + (size_t)(TN - 1) * KXN + CMDN + n];
        else if (n < 362) v = cmds[(size_t)b * (TN * CMDN) + (n - LIDARN)];
        else              v = 0.f;
        lidarcat[idx] = f2b(v);
    }
    if (idx < BATCH * HN) { h0[idx] = 0; cst[idx] = 0.f; }
}

extern "C" void kernel_launch(void* const* d_in, const int* in_sizes, int n_in,
                              void* d_out, int out_size, void* d_ws, size_t ws_size,
                              hipStream_t stream)
{
    const float* past = (const float*)d_in[0];
    const float* cmds = (const float*)d_in[1];
    const float* eWih = (const float*)d_in[2];
    const float* eWhh = (const float*)d_in[3];
    const float* eb   = (const float*)d_in[4];
    const float* dWih = (const float*)d_in[5];
    const float* dWhh = (const float*)d_in[6];
    const float* db   = (const float*)d_in[7];
    const float* oW   = (const float*)d_in[8];
    const float* ob   = (const float*)d_in[9];
    float* out = (float*)d_out;

    char* w = (char*)d_ws;
    auto alloc = [&](size_t bytes) {
        char* p = w; w += (bytes + 255) & ~(size_t)255; return p;
    };
    unsigned short* Wenc = (unsigned short*)alloc((size_t)1024 * KPAD * 2);
    unsigned short* Wdec = (unsigned short*)alloc((size_t)1024 * KPAD * 2);
    unsigned short* oWp  = (unsigned short*)alloc((size_t)384 * HN * 2);
    unsigned short* h0   = (unsigned short*)alloc((size_t)BATCH * HN * 2);
    unsigned short* h1   = (unsigned short*)alloc((size_t)BATCH * HN * 2);
    float*          cst  = (float*)alloc((size_t)BATCH * HN * 4);
    unsigned short* lcat = (unsigned short*)alloc((size_t)BATCH * LCW * 2);

    convert_w<<<(1024 * KPAD + 255) / 256, 256, 0, stream>>>(
        eWih, eWhh, dWih, dWhh, oW, Wenc, Wdec, oWp);
    init_state<<<(BATCH * LCW + 255) / 256, 256, 0, stream>>>(
        past, cmds, h0, cst, lcat);

    unsigned short* hb[2] = {h0, h1};
    int cur = 0;
    dim3 gg(16, BATCH / BM);     // (units/16, batch/64) = (16, 32)
    dim3 og(LCW / BN, BATCH / BM); // (6, 32)

    for (int t = 0; t < TN; ++t) {
        gates_mfma<true><<<gg, 256, 0, stream>>>(
            past + (size_t)t * KXN, nullptr, hb[cur], Wenc, eb, cst, hb[cur ^ 1]);
        cur ^= 1;
    }
    for (int t = 0; t < TN; ++t) {
        gates_mfma<false><<<gg, 256, 0, stream>>>(
            nullptr, lcat, hb[cur], Wdec, db, cst, hb[cur ^ 1]);
        cur ^= 1;
        outproj_mfma<<<og, 256, 0, stream>>>(hb[cur], oWp, ob, cmds, out, lcat, t);
    }
}

// Round 4
// 1997.484 us; speedup vs baseline: 7.0602x; 1.4169x over previous
//
#include <hip/hip_runtime.h>
#include <hip/hip_bf16.h>
#include <math.h>

#define CMDN   2
#define LIDARN 360
#define HN     256
#define TN     50
#define BATCH  2048
#define KXN    362              // CMD+LIDAR
#define NG     1024             // 4*H gate columns
#define KP     384              // padded x-K for big GEMMs
#define MR     (TN*BATCH)       // 102400 rows (t-major: r = t*2048 + b)
#define SLAB   ((size_t)BATCH*HN)

typedef __attribute__((ext_vector_type(8))) short bf16x8;
typedef __attribute__((ext_vector_type(4))) float f32x4;

__device__ inline unsigned short f2b(float f) {
    unsigned int x = __builtin_bit_cast(unsigned int, f);
    x += 0x7FFFu + ((x >> 16) & 1u);
    return (unsigned short)(x >> 16);
}
__device__ inline float b2f(unsigned short u) {
    unsigned int x = ((unsigned int)u) << 16;
    return __builtin_bit_cast(float, x);
}
__device__ inline float sigf(float x)  { return 1.f / (1.f + __expf(-x)); }
__device__ inline float tanhfa(float x){ return 2.f / (1.f + __expf(-2.f * x)) - 1.f; }

// packed gate-col order: p = 4*u + g  ->  original row jorig = g*256 + u
__device__ inline int p2j(int p) { return ((p & 3) << 8) + (p >> 2); }

// ---------------------------------------------------------------------------
// Generic 128x128 MFMA GEMM, A[M][K] bf16, B[N][K] bf16 (both row-major in K).
// OMODE 0: C f32[M][ldc] = acc + bias[col]
// OMODE 1: outproj remap: t=row>>11, b=row&2047; out[b][t][col] = acc + bias[col], col<360
// OMODE 2: C bf16[M][ldc] = acc + bias[col]
// ---------------------------------------------------------------------------
template<int OMODE>
__global__ __launch_bounds__(256) void gemm128(
    const unsigned short* __restrict__ A,
    const unsigned short* __restrict__ B,
    const float* __restrict__ bias,
    void* __restrict__ Cv,
    int K, int ldc)
{
    __shared__ __align__(16) unsigned short As[128][40];
    __shared__ __align__(16) unsigned short Bs[128][40];

    const int tid  = threadIdx.x;
    const int lane = tid & 63;
    const int wv   = tid >> 6;
    const int wm   = wv >> 1, wn = wv & 1;      // 2x2 waves, each 64x64
    const int r0   = blockIdx.y * 128;
    const int n0   = blockIdx.x * 128;
    const int l15  = lane & 15;
    const int kb   = (lane >> 4) << 3;

    const int row1 = tid >> 2, q1 = tid & 3;    // chunk tid
    const int row2 = row1 + 64;                 // chunk tid+256

    f32x4 acc[4][4] = {};

    for (int k0 = 0; k0 < K; k0 += 32) {
        *(bf16x8*)&As[row1][q1 * 8] = *(const bf16x8*)&A[(size_t)(r0 + row1) * K + k0 + q1 * 8];
        *(bf16x8*)&As[row2][q1 * 8] = *(const bf16x8*)&A[(size_t)(r0 + row2) * K + k0 + q1 * 8];
        *(bf16x8*)&Bs[row1][q1 * 8] = *(const bf16x8*)&B[(size_t)(n0 + row1) * K + k0 + q1 * 8];
        *(bf16x8*)&Bs[row2][q1 * 8] = *(const bf16x8*)&B[(size_t)(n0 + row2) * K + k0 + q1 * 8];
        __syncthreads();
        bf16x8 a[4], b[4];
        #pragma unroll
        for (int i = 0; i < 4; ++i) {
            a[i] = *(const bf16x8*)&As[wm * 64 + i * 16 + l15][kb];
            b[i] = *(const bf16x8*)&Bs[wn * 64 + i * 16 + l15][kb];
        }
        #pragma unroll
        for (int mi = 0; mi < 4; ++mi)
            #pragma unroll
            for (int ni = 0; ni < 4; ++ni)
                acc[mi][ni] = __builtin_amdgcn_mfma_f32_16x16x32_bf16(a[mi], b[ni], acc[mi][ni], 0, 0, 0);
        __syncthreads();
    }

    #pragma unroll
    for (int mi = 0; mi < 4; ++mi) {
        const int rowb = r0 + wm * 64 + mi * 16 + ((lane >> 4) << 2);
        #pragma unroll
        for (int ni = 0; ni < 4; ++ni) {
            const int col = n0 + wn * 64 + ni * 16 + l15;
            #pragma unroll
            for (int r = 0; r < 4; ++r) {
                const int row = rowb + r;
                float v = acc[mi][ni][r];
                if (OMODE == 0) {
                    ((float*)Cv)[(size_t)row * ldc + col] = v + bias[col];
                } else if (OMODE == 2) {
                    ((unsigned short*)Cv)[(size_t)row * ldc + col] = f2b(v + bias[col]);
                } else {
                    if (col < LIDARN) {
                        int t = row >> 11, b = row & 2047;
                        ((float*)Cv)[(size_t)b * (TN * LIDARN) + (size_t)t * LIDARN + col] = v + bias[col];
                    }
                }
            }
        }
    }
}

// ---------------------------------------------------------------------------
// Recurrent step: gates = h_in @ W^T (K=256) + additive, fused LSTM cell.
// MODE 0 (enc):  additive = bf16 xw_t[2048][1024] (contains x@Wih + eb)
// MODE 1 (dec0): additive = f32 l0w[2048][1024] (lidar0@Wl + db) + inline cmd
// MODE 2 (dec):  additive = biasf[p] + inline cmd      (W = Wcomb)
// Tile 64x64, BK=64, 4 waves 2x2 (each 32x32).
// ---------------------------------------------------------------------------
template<int MODE>
__global__ __launch_bounds__(256) void step_kernel(
    const unsigned short* __restrict__ hin,
    const unsigned short* __restrict__ W,
    const unsigned short* __restrict__ addb,
    const float* __restrict__ addf,
    const float* __restrict__ biasp,
    const float* __restrict__ cmdw,     // [1024][2] f32 packed
    const float* __restrict__ cmds_t,   // cmds + t*2, row stride 100
    float* __restrict__ cst,
    unsigned short* __restrict__ hout)
{
    __shared__ __align__(16) unsigned short As[64][72];
    __shared__ __align__(16) unsigned short Bs[64][72];

    const int tid  = threadIdx.x;
    const int lane = tid & 63;
    const int wv   = tid >> 6;
    const int wm   = wv >> 1, wn = wv & 1;
    const int r0   = blockIdx.y * 64;
    const int pb   = blockIdx.x * 64;
    const int l15  = lane & 15;
    const int kb   = (lane >> 4) << 3;

    const int row1 = tid >> 3, o1 = tid & 7;    // chunks tid, tid+256
    const int row2 = row1 + 32;

    f32x4 acc[2][2] = {};

    #pragma unroll
    for (int k0 = 0; k0 < HN; k0 += 64) {
        *(bf16x8*)&As[row1][o1 * 8] = *(const bf16x8*)&hin[(size_t)(r0 + row1) * HN + k0 + o1 * 8];
        *(bf16x8*)&As[row2][o1 * 8] = *(const bf16x8*)&hin[(size_t)(r0 + row2) * HN + k0 + o1 * 8];
        *(bf16x8*)&Bs[row1][o1 * 8] = *(const bf16x8*)&W[(size_t)(pb + row1) * HN + k0 + o1 * 8];
        *(bf16x8*)&Bs[row2][o1 * 8] = *(const bf16x8*)&W[(size_t)(pb + row2) * HN + k0 + o1 * 8];
        __syncthreads();
        #pragma unroll
        for (int kh = 0; kh < 2; ++kh) {
            const int kk = kh * 32 + kb;
            bf16x8 a0 = *(const bf16x8*)&As[wm * 32 +      l15][kk];
            bf16x8 a1 = *(const bf16x8*)&As[wm * 32 + 16 + l15][kk];
            bf16x8 b0 = *(const bf16x8*)&Bs[wn * 32 +      l15][kk];
            bf16x8 b1 = *(const bf16x8*)&Bs[wn * 32 + 16 + l15][kk];
            acc[0][0] = __builtin_amdgcn_mfma_f32_16x16x32_bf16(a0, b0, acc[0][0], 0, 0, 0);
            acc[0][1] = __builtin_amdgcn_mfma_f32_16x16x32_bf16(a0, b1, acc[0][1], 0, 0, 0);
            acc[1][0] = __builtin_amdgcn_mfma_f32_16x16x32_bf16(a1, b0, acc[1][0], 0, 0, 0);
            acc[1][1] = __builtin_amdgcn_mfma_f32_16x16x32_bf16(a1, b1, acc[1][1], 0, 0, 0);
        }
        __syncthreads();
    }

    #pragma unroll
    for (int mi = 0; mi < 2; ++mi) {
        const int rowb = r0 + wm * 32 + mi * 16 + ((lane >> 4) << 2);
        #pragma unroll
        for (int ni = 0; ni < 2; ++ni) {
            const int cl = wn * 32 + ni * 16 + l15;
            const int p  = pb + cl;
            const int g  = cl & 3;                 // 0=i 1=f 2=g 3=o
            const int u  = p >> 2;
            float bsv = 0.f, w0 = 0.f, w1 = 0.f;
            if (MODE == 2) bsv = biasp[p];
            if (MODE >= 1) { w0 = cmdw[p * 2]; w1 = cmdw[p * 2 + 1]; }
            #pragma unroll
            for (int r = 0; r < 4; ++r) {
                const int row = rowb + r;
                float v = acc[mi][ni][r];
                if (MODE == 0) v += b2f(addb[(size_t)row * NG + p]);
                if (MODE == 1) v += addf[(size_t)row * NG + p]
                                  + cmds_t[row * (TN * CMDN)] * w0
                                  + cmds_t[row * (TN * CMDN) + 1] * w1;
                if (MODE == 2) v += bsv
                                  + cmds_t[row * (TN * CMDN)] * w0
                                  + cmds_t[row * (TN * CMDN) + 1] * w1;
                float act = (g == 2) ? tanhfa(v) : sigf(v);
                float a1  = __shfl_xor(act, 1);
                float a2  = __shfl_xor(act, 2);
                float a3  = __shfl_xor(act, 3);
                if (g == 0) {
                    size_t idx = (size_t)row * HN + u;
                    float cc = a1 * cst[idx] + act * a2;
                    float hh = a3 * tanhfa(cc);
                    cst[idx]  = cc;
                    hout[idx] = f2b(hh);
                }
            }
        }
    }
}

// ---------------------------------------------------------------------------
// Packs
// ---------------------------------------------------------------------------
__global__ __launch_bounds__(256) void pack_x(
    const float* __restrict__ past, unsigned short* __restrict__ Xb)
{
    int idx = blockIdx.x * 256 + threadIdx.x;        // over MR*KP
    if (idx >= MR * KP) return;
    int r = idx / KP, k = idx - r * KP;
    int b = r & 2047, t = r >> 11;
    Xb[idx] = (k < KXN) ? f2b(past[((size_t)b * TN + t) * KXN + k]) : (unsigned short)0;
}

__global__ __launch_bounds__(256) void pack_w(
    const float* __restrict__ past,
    const float* __restrict__ eWih, const float* __restrict__ eWhh, const float* __restrict__ eb,
    const float* __restrict__ dWih, const float* __restrict__ dWhh, const float* __restrict__ db,
    const float* __restrict__ oW,
    unsigned short* __restrict__ L0b,      // [2048][384]
    unsigned short* __restrict__ Wihe_p,   // [1024][384]
    unsigned short* __restrict__ Wdihl_p,  // [1024][384]
    unsigned short* __restrict__ Whhe_p,   // [1024][256]
    unsigned short* __restrict__ Wdhh_p,   // [1024][256]
    unsigned short* __restrict__ oWp,      // [384][256]
    float* __restrict__ Wc_p,              // [1024][2]
    float* __restrict__ ebp, float* __restrict__ dbp)
{
    int idx = blockIdx.x * 256 + threadIdx.x;
    if (idx < BATCH * KP) {                // L0b: lidar0 = past[:, -1, 2:]
        int b = idx / KP, k = idx - b * KP;
        L0b[idx] = (k < LIDARN)
            ? f2b(past[((size_t)b * TN + (TN - 1)) * KXN + CMDN + k]) : (unsigned short)0;
    }
    if (idx < NG * KP) {
        int p = idx / KP, k = idx - p * KP;
        int j = p2j(p);
        Wihe_p[idx]  = (k < KXN)    ? f2b(eWih[(size_t)j * KXN + k]) : (unsigned short)0;
        Wdihl_p[idx] = (k < LIDARN) ? f2b(dWih[(size_t)j * KXN + k]) : (unsigned short)0;
        if (k < HN) {
            Whhe_p[p * HN + k] = f2b(eWhh[(size_t)j * HN + k]);
            Wdhh_p[p * HN + k] = f2b(dWhh[(size_t)j * HN + k]);
        }
        if (k < 2) Wc_p[p * 2 + k] = dWih[(size_t)j * KXN + LIDARN + k];
        if (k == 0) { ebp[p] = eb[j]; dbp[p] = db[j]; }
    }
    if (idx < KP * HN) {
        int n = idx / HN, k = idx - n * HN;
        oWp[idx] = (n < LIDARN) ? f2b(oW[(size_t)n * HN + k]) : (unsigned short)0;
    }
}

// Wcomb[p][k] = dWhh[j][k] + sum_n dWih[j][n] * oW[n][k]
__global__ __launch_bounds__(256) void wcomb_kernel(
    const float* __restrict__ dWih, const float* __restrict__ dWhh,
    const float* __restrict__ oW, unsigned short* __restrict__ Wcomb_p)
{
    int p = blockIdx.x, k = threadIdx.x;
    int j = p2j(p);
    float s = dWhh[(size_t)j * HN + k];
    for (int n = 0; n < LIDARN; ++n)
        s += dWih[(size_t)j * KXN + n] * oW[(size_t)n * HN + k];
    Wcomb_p[(size_t)p * HN + k] = f2b(s);
}

// biasf[p] = db[j] + sum_n dWih[j][n] * ob[n]
__global__ __launch_bounds__(256) void biasf_kernel(
    const float* __restrict__ dWih, const float* __restrict__ db,
    const float* __restrict__ ob, float* __restrict__ biasf)
{
    int p = blockIdx.x * 256 + threadIdx.x;
    if (p >= NG) return;
    int j = p2j(p);
    float s = db[j];
    for (int n = 0; n < LIDARN; ++n)
        s += dWih[(size_t)j * KXN + n] * ob[n];
    biasf[p] = s;
}

__global__ __launch_bounds__(256) void init_hc(
    unsigned short* __restrict__ h0, float* __restrict__ cst)
{
    int idx = blockIdx.x * 256 + threadIdx.x;
    if (idx < BATCH * HN) { h0[idx] = 0; cst[idx] = 0.f; }
}

extern "C" void kernel_launch(void* const* d_in, const int* in_sizes, int n_in,
                              void* d_out, int out_size, void* d_ws, size_t ws_size,
                              hipStream_t stream)
{
    const float* past = (const float*)d_in[0];
    const float* cmds = (const float*)d_in[1];
    const float* eWih = (const float*)d_in[2];
    const float* eWhh = (const float*)d_in[3];
    const float* eb   = (const float*)d_in[4];
    const float* dWih = (const float*)d_in[5];
    const float* dWhh = (const float*)d_in[6];
    const float* db   = (const float*)d_in[7];
    const float* oW   = (const float*)d_in[8];
    const float* ob   = (const float*)d_in[9];
    float* out = (float*)d_out;

    char* w = (char*)d_ws;
    auto alloc = [&](size_t bytes) {
        char* p = w; w += (bytes + 255) & ~(size_t)255; return p;
    };
    unsigned short* xw      = (unsigned short*)alloc((size_t)MR * NG * 2);      // 209.7 MB bf16
    unsigned short* Xb      = (unsigned short*)alloc((size_t)MR * KP * 2);      // 78.6 MB
    unsigned short* hdec    = Xb;                                               // alias (Xb dead after xw GEMM)
    float*          l0w     = (float*)alloc((size_t)BATCH * NG * 4);            // 8.4 MB
    unsigned short* L0b     = (unsigned short*)alloc((size_t)BATCH * KP * 2);
    unsigned short* Wihe_p  = (unsigned short*)alloc((size_t)NG * KP * 2);
    unsigned short* Wdihl_p = (unsigned short*)alloc((size_t)NG * KP * 2);
    unsigned short* Whhe_p  = (unsigned short*)alloc((size_t)NG * HN * 2);
    unsigned short* Wdhh_p  = (unsigned short*)alloc((size_t)NG * HN * 2);
    unsigned short* Wcomb_p = (unsigned short*)alloc((size_t)NG * HN * 2);
    unsigned short* oWp     = (unsigned short*)alloc((size_t)KP * HN * 2);
    float*          Wc_p    = (float*)alloc((size_t)NG * 2 * 4);
    float*          ebp     = (float*)alloc(NG * 4);
    float*          dbp     = (float*)alloc(NG * 4);
    float*          biasf   = (float*)alloc(NG * 4);
    unsigned short* h0      = (unsigned short*)alloc(SLAB * 2);
    unsigned short* h1      = (unsigned short*)alloc(SLAB * 2);
    float*          cst     = (float*)alloc(SLAB * 4);

    pack_x<<<(MR * KP + 255) / 256, 256, 0, stream>>>(past, Xb);
    pack_w<<<(BATCH * KP + 255) / 256, 256, 0, stream>>>(
        past, eWih, eWhh, eb, dWih, dWhh, db, oW,
        L0b, Wihe_p, Wdihl_p, Whhe_p, Wdhh_p, oWp, Wc_p, ebp, dbp);
    wcomb_kernel<<<NG, 256, 0, stream>>>(dWih, dWhh, oW, Wcomb_p);
    biasf_kernel<<<(NG + 255) / 256, 256, 0, stream>>>(dWih, db, ob, biasf);
    init_hc<<<(BATCH * HN + 255) / 256, 256, 0, stream>>>(h0, cst);

    // xw = Xb @ Wihe^T + eb  (bf16 out), [50][2048][1024]
    gemm128<2><<<dim3(NG / 128, MR / 128), 256, 0, stream>>>(Xb, Wihe_p, ebp, xw, KP, NG);
    // l0w = lidar0 @ Wl^T + db (f32)
    gemm128<0><<<dim3(NG / 128, BATCH / 128), 256, 0, stream>>>(L0b, Wdihl_p, dbp, l0w, KP, NG);

    const dim3 sg(NG / 64, BATCH / 64);   // (16, 32)

    unsigned short* hb[2] = {h0, h1};
    int cur = 0;
    for (int t = 0; t < TN; ++t) {
        step_kernel<0><<<sg, 256, 0, stream>>>(
            hb[cur], Whhe_p, xw + (size_t)t * BATCH * NG,
            nullptr, nullptr, nullptr, nullptr, cst, hb[cur ^ 1]);
        cur ^= 1;
    }

    // decoder step 0: original form (lidar0 path), B = dWhh
    step_kernel<1><<<sg, 256, 0, stream>>>(
        hb[cur], Wdhh_p, nullptr, l0w, nullptr, Wc_p, cmds, cst, hdec);
    // decoder steps 1..49: folded recurrence, B = Wcomb
    for (int t = 1; t < TN; ++t) {
        step_kernel<2><<<sg, 256, 0, stream>>>(
            hdec + (size_t)(t - 1) * SLAB, Wcomb_p, nullptr, nullptr, biasf,
            Wc_p, cmds + (size_t)t * CMDN, cst, hdec + (size_t)t * SLAB);
    }

    // out[b][t][n] = hdec[t][b] @ oW^T + ob
    gemm128<1><<<dim3(KP / 128, MR / 128), 256, 0, stream>>>(hdec, oWp, ob, out, HN, 0);
}